// Round 1
// 681.323 us; speedup vs baseline: 1.2888x; 1.2888x over previous
//
#include <hip/hip_runtime.h>

typedef unsigned short ush;
typedef __attribute__((ext_vector_type(8))) __bf16 bf16x8;
typedef __attribute__((ext_vector_type(4))) float f32x4;

#define NE 33554432L  // 4*128*128*512 elements per Q/K/V matrix

// ---------- bf16 <-> fp32 helpers (RNE) ----------
__device__ __forceinline__ float b2f(ush u) {
  return __uint_as_float(((unsigned int)u) << 16);
}
__device__ __forceinline__ ush f2b(float f) {
  unsigned int x = __float_as_uint(f);
  x += 0x7fffu + ((x >> 16) & 1u);
  return (ush)(x >> 16);
}
__device__ __forceinline__ bf16x8 bc8(int4 v) { return __builtin_bit_cast(bf16x8, v); }

// async 16B global->LDS (wave-uniform LDS base + lane*16)
__device__ __forceinline__ void gload16(const ush* g, ush* l) {
  __builtin_amdgcn_global_load_lds(
      (const __attribute__((address_space(1))) void*)g,
      (__attribute__((address_space(3))) void*)l, 16, 0, 0);
}

// ---------- kernel: input dtype sniffer ----------
// flag[0] = 1 if inputs are bf16, 0 if fp32 (fp32-as-ushort exponents are junk).
__global__ __launch_bounds__(256)
void detect_dtype(const ush* __restrict__ x, int* __restrict__ flag) {
  __shared__ int red[256];
  const int t = threadIdx.x;
  int cnt = 0;
  for (int i = t; i < 16384; i += 256) {
    const int e = (x[i] >> 7) & 0xFF;
    cnt += (e == 0 || (e >= 100 && e <= 142)) ? 1 : 0;
  }
  red[t] = cnt;
  __syncthreads();
  for (int s = 128; s > 0; s >>= 1) {
    if (t < s) red[t] += red[t + s];
    __syncthreads();
  }
  if (t == 0) flag[0] = (red[0] >= 13107) ? 1 : 0;  // 80% of 16384
}

// ---------- kernel: pack x -> bf16 ----------
__global__ __launch_bounds__(256)
void pack_x(const void* __restrict__ xin, ush* __restrict__ xb,
            const int* __restrict__ flag) {
  const long i0 = ((long)blockIdx.x * 256 + threadIdx.x) * 8;
  if (*flag) {
    *(int4*)&xb[i0] = *(const int4*)&((const ush*)xin)[i0];
  } else {
    const float* xf = (const float*)xin;
    const float4 a = *(const float4*)&xf[i0];
    const float4 b = *(const float4*)&xf[i0 + 4];
    union { ush u[8]; int4 v; } r;
    r.u[0] = f2b(a.x); r.u[1] = f2b(a.y); r.u[2] = f2b(a.z); r.u[3] = f2b(a.w);
    r.u[4] = f2b(b.x); r.u[5] = f2b(b.y); r.u[6] = f2b(b.z); r.u[7] = f2b(b.w);
    *(int4*)&xb[i0] = r.v;
  }
}

// ---------- kernel: pack+transpose weights -> bf16 wT[n][k] = w[k][n] ----------
__global__ __launch_bounds__(256)
void pack_w(const void* __restrict__ w0, const void* __restrict__ w1,
            const void* __restrict__ w2, ush* __restrict__ wTb,
            const int* __restrict__ flag) {
  __shared__ ush tile[32][33];
  const void* w = (blockIdx.z == 0) ? w0 : ((blockIdx.z == 1) ? w1 : w2);
  ush* wT = wTb + (long)blockIdx.z * 262144;
  const int bx = blockIdx.x * 32, by = blockIdx.y * 32;
  const int tx = threadIdx.x & 31, ty = threadIdx.x >> 5;
  const int f = *flag;
#pragma unroll
  for (int j = 0; j < 32; j += 8) {
    const int k = by + ty + j, n = bx + tx;
    tile[ty + j][tx] = f ? ((const ush*)w)[k * 512 + n]
                         : f2b(((const float*)w)[k * 512 + n]);
  }
  __syncthreads();
#pragma unroll
  for (int j = 0; j < 32; j += 8)
    wT[(bx + ty + j) * 512 + by + tx] = tile[tx][ty + j];
}

// ---------- kernel: pack biases -> fp32 ----------
__global__ void pack_bias(const void* __restrict__ b0, const void* __restrict__ b1,
                          const void* __restrict__ b2, float* __restrict__ biasf,
                          const int* __restrict__ flag) {
  const void* b = (blockIdx.x == 0) ? b0 : ((blockIdx.x == 1) ? b1 : b2);
  const int n = threadIdx.x;
  const float v = (*flag) ? b2f(((const ush*)b)[n]) : ((const float*)b)[n];
  biasf[blockIdx.x * 512 + n] = v;
}

// ---------- kernel: QKV projection GEMM (m97 structure) ----------
// 128x128 tile, BK=32, 4 waves (2x2 of 64x64). A and B tiles staged to LDS via
// global_load_lds width-16 (linear LDS dest, pre-swizzled global source so the
// ds_read_b128 fragment reads are bank-conflict-free: slot j of row r holds
// global k8 = j ^ ((r>>1)&3); on read, quad -> slot quad ^ ((col>>1)&3)).
__global__ __launch_bounds__(256)
void proj_gemm(const ush* __restrict__ xb, const ush* __restrict__ wTb,
               const float* __restrict__ biasf, ush* __restrict__ qkv) {
  __shared__ ush As[4096];  // [128 rows][32 k] bf16, 8 KB, linear
  __shared__ ush Bs[4096];

  const int z = blockIdx.z;
  const ush* wt = wTb + (long)z * 262144;
  const float* bias = biasf + z * 512;
  ush* out = qkv + (long)z * NE;

  const int t = threadIdx.x;
  const int lane = t & 63;
  const int wvid = t >> 6;
  const int wm = wvid & 1, wn = wvid >> 1;
  const int col = lane & 15, quad = lane >> 4;

  const long m0 = (long)blockIdx.y * 128;
  const int n0 = blockIdx.x * 128;

  // ---- staging addresses: group g = wvid*2+c covers tile rows g*16..g*16+15
  // (= 1024 B of LDS, exactly one wave-wide 16B/lane global_load_lds).
  // lane l -> row g*16 + (l>>2), slot (l&3); source k8 pre-swizzled.
  const int r_in_g = lane >> 2;
  const int swz = (((lane & 3) ^ ((r_in_g >> 1) & 3)) * 8);
  const int g0 = wvid * 2, g1 = g0 + 1;
  const ush* gA0 = xb + (m0 + g0 * 16 + r_in_g) * 512 + swz;
  const ush* gA1 = xb + (m0 + g1 * 16 + r_in_g) * 512 + swz;
  const ush* gB0 = wt + (long)(n0 + g0 * 16 + r_in_g) * 512 + swz;
  const ush* gB1 = wt + (long)(n0 + g1 * 16 + r_in_g) * 512 + swz;
  ush* lA0 = &As[g0 * 512];
  ush* lA1 = &As[g1 * 512];
  ush* lB0 = &Bs[g0 * 512];
  ush* lB1 = &Bs[g1 * 512];

  // ---- fragment ds_read offsets (row = 16*i + col  =>  f(row) = (col>>1)&3)
  const int kswz = ((quad ^ ((col >> 1) & 3)) * 8);
  int aofs[4], bofs[4];
#pragma unroll
  for (int i = 0; i < 4; i++) aofs[i] = (wm * 64 + i * 16 + col) * 32 + kswz;
#pragma unroll
  for (int j = 0; j < 4; j++) bofs[j] = (wn * 64 + j * 16 + col) * 32 + kswz;

  const f32x4 z4 = {0.f, 0.f, 0.f, 0.f};
  f32x4 acc[4][4];
#pragma unroll
  for (int i = 0; i < 4; i++)
#pragma unroll
    for (int j = 0; j < 4; j++) acc[i][j] = z4;

  for (int k0 = 0; k0 < 512; k0 += 32) {
    gload16(gA0 + k0, lA0);
    gload16(gA1 + k0, lA1);
    gload16(gB0 + k0, lB0);
    gload16(gB1 + k0, lB1);
    __syncthreads();  // drains vmcnt (compiler-inserted) -> tiles ready
    bf16x8 a[4], b[4];
#pragma unroll
    for (int i = 0; i < 4; i++) a[i] = bc8(*(const int4*)&As[aofs[i]]);
#pragma unroll
    for (int j = 0; j < 4; j++) b[j] = bc8(*(const int4*)&Bs[bofs[j]]);
#pragma unroll
    for (int i = 0; i < 4; i++)
#pragma unroll
      for (int j = 0; j < 4; j++)
        acc[i][j] = __builtin_amdgcn_mfma_f32_16x16x32_bf16(a[i], b[j], acc[i][j], 0, 0, 0);
    __syncthreads();  // all reads done before next stage overwrites
  }

#pragma unroll
  for (int j = 0; j < 4; j++) {
    const int n = n0 + wn * 64 + j * 16 + col;
    const float bb = bias[n];
#pragma unroll
    for (int i = 0; i < 4; i++) {
      const long row0 = m0 + wm * 64 + i * 16 + quad * 4;
#pragma unroll
      for (int r = 0; r < 4; r++)
        out[(row0 + r) * 512 + n] = f2b(acc[i][j][r] + bb);
    }
  }
}

// ---------- MFMA axial attention ----------
// PASS 1 (column): block (b,n,w); rows = H; writes xv in-place over V (bf16).
// PASS 2 (row):    block (b,n,h); rows = W; V buffer holds xv; writes output.
// Per block: S = Q*K^T (128x128x64) -> softmax -> xv = P*V (128x128x128),
// all matmuls on MFMA. LDS 54272 B -> 3 blocks/CU.
#define QS_STRIDE 72    // bf16, 144 B rows (16B aligned), uniform bank groups
#define VT_STRIDE 136   // Vt[d][g], 272 B rows
#define P_STRIDE  136

// XOR swizzle on g-blocks of Vt: breaks the 16-way write conflict (d-block
// coefficient 1088 ush aliases to bank 0 without it), keeps 8-contig g for b128.
__device__ __forceinline__ int vt_idx(int d, int g) {
  return d * VT_STRIDE + ((((g >> 3) ^ ((d >> 3) & 7)) << 3) | (g & 7));
}

template<int PASS>
__global__ __launch_bounds__(256, 3)
void axial_attn_mfma(const ush* __restrict__ Qb, const ush* __restrict__ Kb,
                     ush* __restrict__ Vb, void* __restrict__ outp,
                     const int* __restrict__ flagp) {
  __shared__ ush smem[27136];          // 54272 B
  ush* Qs = smem;                      // [128][72]
  ush* Ks = smem + 9216;               // [128][72]
  ush* Vt = smem + 18432;              // [64][136] swizzled
  ush* P  = smem;                      // [128][136] overlays Qs+Ks after barrier1

  const int flg = *flagp;
  const int b = blockIdx.z, n = blockIdx.y, pp = blockIdx.x;
  long base; int stride;
  if (PASS == 1) { base = ((long)b * 16384 + pp) * 512 + n * 64; stride = 65536; }
  else           { base = ((long)(b * 128 + pp) * 128) * 512 + n * 64; stride = 512; }

  const int t = threadIdx.x;
  // phase 0: stage Q,K row-major; V transposed (swizzled)
#pragma unroll
  for (int it = 0; it < 4; it++) {
    const int c = t + it * 256;
    const int row = c >> 3, c8 = c & 7;
    const long g = base + (long)row * stride + c8 * 8;
    int4 q = *(const int4*)(Qb + g);
    int4 k = *(const int4*)(Kb + g);
    int4 v = *(const int4*)(Vb + g);
    *(int4*)&Qs[row * QS_STRIDE + c8 * 8] = q;
    *(int4*)&Ks[row * QS_STRIDE + c8 * 8] = k;
    union { int4 i4; ush u[8]; } vu; vu.i4 = v;
#pragma unroll
    for (int dd = 0; dd < 8; dd++)
      Vt[vt_idx(c8 * 8 + dd, row)] = vu.u[dd];
  }
  __syncthreads();

  const int lane = t & 63, wv = t >> 6;
  const int col = lane & 15, quad = lane >> 4;
  const int m0 = wv * 32;  // wave owns rows m0..m0+31, all 128 cols
  const f32x4 z4 = {0.f, 0.f, 0.f, 0.f};

  // ---- S = Q K^T : 2 m-tiles x 8 n-tiles x 2 k-steps ----
  f32x4 sacc[2][8];
#pragma unroll
  for (int i = 0; i < 2; i++)
#pragma unroll
    for (int j = 0; j < 8; j++) sacc[i][j] = z4;
#pragma unroll
  for (int k0 = 0; k0 < 64; k0 += 32) {
    bf16x8 a[2], kb[8];
#pragma unroll
    for (int i = 0; i < 2; i++)
      a[i] = bc8(*(const int4*)&Qs[(m0 + i * 16 + col) * QS_STRIDE + k0 + quad * 8]);
#pragma unroll
    for (int j = 0; j < 8; j++)
      kb[j] = bc8(*(const int4*)&Ks[(j * 16 + col) * QS_STRIDE + k0 + quad * 8]);
#pragma unroll
    for (int i = 0; i < 2; i++)
#pragma unroll
      for (int j = 0; j < 8; j++)
        sacc[i][j] = __builtin_amdgcn_mfma_f32_16x16x32_bf16(a[i], kb[j], sacc[i][j], 0, 0, 0);
  }

  // ---- softmax (faithful: clip +-(1-eps), /8, exp, sum, clip [eps,1-eps]) ----
  const float CLIP = 1.0f - 1e-7f;
  float e[2][8][4], inv[2][4];
#pragma unroll
  for (int i = 0; i < 2; i++)
#pragma unroll
    for (int r = 0; r < 4; r++) {
      float part = 0.f;
#pragma unroll
      for (int j = 0; j < 8; j++) {
        float s = sacc[i][j][r];
        s = fminf(fmaxf(s, -CLIP), CLIP) * 0.125f;
        const float ee = __expf(s);
        e[i][j][r] = ee;
        part += ee;
      }
      part += __shfl_xor(part, 1);
      part += __shfl_xor(part, 2);
      part += __shfl_xor(part, 4);
      part += __shfl_xor(part, 8);
      inv[i][r] = 1.0f / part;
    }
  __syncthreads();  // barrier1: all Qs/Ks reads complete -> safe to overlay P

  // lane's rows: m0 + 16i + 4*quad + r; cols: 16j + col (C/D layout, m89)
#pragma unroll
  for (int i = 0; i < 2; i++)
#pragma unroll
    for (int r = 0; r < 4; r++) {
      const int row = m0 + i * 16 + quad * 4 + r;
#pragma unroll
      for (int j = 0; j < 8; j++) {
        const float pv = fminf(fmaxf(e[i][j][r] * inv[i][r], 1e-7f), CLIP);
        P[row * P_STRIDE + j * 16 + col] = f2b(pv);
      }
    }
  __syncthreads();  // barrier2: P complete

  // ---- xv = P V : 2 m-tiles x 4 n-tiles x 4 k-steps ----
  f32x4 oacc[2][4];
#pragma unroll
  for (int i = 0; i < 2; i++)
#pragma unroll
    for (int j = 0; j < 4; j++) oacc[i][j] = z4;
#pragma unroll
  for (int k0 = 0; k0 < 128; k0 += 32) {
    bf16x8 a[2], vb[4];
#pragma unroll
    for (int i = 0; i < 2; i++)
      a[i] = bc8(*(const int4*)&P[(m0 + i * 16 + col) * P_STRIDE + k0 + quad * 8]);
#pragma unroll
    for (int j = 0; j < 4; j++)
      vb[j] = bc8(*(const int4*)&Vt[vt_idx(j * 16 + col, k0 + quad * 8)]);
#pragma unroll
    for (int i = 0; i < 2; i++)
#pragma unroll
      for (int j = 0; j < 4; j++)
        oacc[i][j] = __builtin_amdgcn_mfma_f32_16x16x32_bf16(a[i], vb[j], oacc[i][j], 0, 0, 0);
  }

  // ---- epilogue ----
#pragma unroll
  for (int i = 0; i < 2; i++)
#pragma unroll
    for (int r = 0; r < 4; r++) {
      const int row = m0 + i * 16 + quad * 4 + r;
#pragma unroll
      for (int j = 0; j < 4; j++) {
        const int d = j * 16 + col;
        const float val = oacc[i][j][r];
        if (PASS == 1) {
          Vb[base + (long)row * stride + d] = f2b(val);
        } else {
          const long oi = ((long)(b * 128 + pp) * 128 + row) * 512 + d * 8 + n;
          if (flg) ((ush*)outp)[oi] = f2b(val);
          else     ((float*)outp)[oi] = val;
        }
      }
    }
}

// ---------- host ----------
extern "C" void kernel_launch(void* const* d_in, const int* in_sizes, int n_in,
                              void* d_out, int out_size, void* d_ws, size_t ws_size,
                              hipStream_t stream) {
  const void* x  = d_in[0];
  const void* wq = d_in[1];
  const void* bq = d_in[2];
  const void* wk = d_in[3];
  const void* bk = d_in[4];
  const void* wv = d_in[5];
  const void* bv = d_in[6];

  char* ws = (char*)d_ws;
  int*   flag  = (int*)ws;                       // @0
  float* biasf = (float*)(ws + 256);             // 3*512 fp32
  ush*   wTb   = (ush*)(ws + 8192);              // 1.5 MB
  ush*   xb    = (ush*)(ws + 8192 + 1572864);    // 64 MB
  ush*   qkv   = (ush*)(ws + 8192 + 1572864 + 67108864);  // 3*64 MB bf16

  dim3 blk(256);
  detect_dtype<<<1, blk, 0, stream>>>((const ush*)x, flag);
  pack_bias<<<3, 512, 0, stream>>>(bq, bk, bv, biasf, flag);
  pack_w<<<dim3(16, 16, 3), blk, 0, stream>>>(wq, wk, wv, wTb, flag);
  pack_x<<<16384, blk, 0, stream>>>(x, xb, flag);

  ush* Q = qkv;
  ush* K = Q + NE;
  ush* V = K + NE;
  proj_gemm<<<dim3(4, 512, 3), blk, 0, stream>>>(xb, wTb, biasf, Q);
  dim3 agrid(128, 8, 4);
  axial_attn_mfma<1><<<agrid, blk, 0, stream>>>(Q, K, V, d_out, flag);
  axial_attn_mfma<2><<<agrid, blk, 0, stream>>>(Q, K, V, d_out, flag);
}

// Round 2
// 589.951 us; speedup vs baseline: 1.4884x; 1.1549x over previous
//
#include <hip/hip_runtime.h>

typedef unsigned short ush;
typedef __attribute__((ext_vector_type(8))) __bf16 bf16x8;
typedef __attribute__((ext_vector_type(4))) float f32x4;

#define NE 33554432L  // 4*128*128*512 elements per Q/K/V matrix

// ---------- bf16 <-> fp32 helpers (RNE) ----------
__device__ __forceinline__ float b2f(ush u) {
  return __uint_as_float(((unsigned int)u) << 16);
}
__device__ __forceinline__ ush f2b(float f) {
  unsigned int x = __float_as_uint(f);
  x += 0x7fffu + ((x >> 16) & 1u);
  return (ush)(x >> 16);
}
__device__ __forceinline__ bf16x8 bc8(int4 v) { return __builtin_bit_cast(bf16x8, v); }

// async 16B global->LDS (wave-uniform LDS base + lane*16)
__device__ __forceinline__ void gload16(const ush* g, ush* l) {
  __builtin_amdgcn_global_load_lds(
      (const __attribute__((address_space(1))) void*)g,
      (__attribute__((address_space(3))) void*)l, 16, 0, 0);
}

// ---------- kernel: input dtype sniffer ----------
__global__ __launch_bounds__(256)
void detect_dtype(const ush* __restrict__ x, int* __restrict__ flag) {
  __shared__ int red[256];
  const int t = threadIdx.x;
  int cnt = 0;
  for (int i = t; i < 16384; i += 256) {
    const int e = (x[i] >> 7) & 0xFF;
    cnt += (e == 0 || (e >= 100 && e <= 142)) ? 1 : 0;
  }
  red[t] = cnt;
  __syncthreads();
  for (int s = 128; s > 0; s >>= 1) {
    if (t < s) red[t] += red[t + s];
    __syncthreads();
  }
  if (t == 0) flag[0] = (red[0] >= 13107) ? 1 : 0;  // 80% of 16384
}

// ---------- kernel: pack x -> bf16 ----------
__global__ __launch_bounds__(256)
void pack_x(const void* __restrict__ xin, ush* __restrict__ xb,
            const int* __restrict__ flag) {
  const long i0 = ((long)blockIdx.x * 256 + threadIdx.x) * 8;
  if (*flag) {
    *(int4*)&xb[i0] = *(const int4*)&((const ush*)xin)[i0];
  } else {
    const float* xf = (const float*)xin;
    const float4 a = *(const float4*)&xf[i0];
    const float4 b = *(const float4*)&xf[i0 + 4];
    union { ush u[8]; int4 v; } r;
    r.u[0] = f2b(a.x); r.u[1] = f2b(a.y); r.u[2] = f2b(a.z); r.u[3] = f2b(a.w);
    r.u[4] = f2b(b.x); r.u[5] = f2b(b.y); r.u[6] = f2b(b.z); r.u[7] = f2b(b.w);
    *(int4*)&xb[i0] = r.v;
  }
}

// ---------- kernel: pack+transpose weights -> bf16 wT[n][k] = w[k][n] ----------
__global__ __launch_bounds__(256)
void pack_w(const void* __restrict__ w0, const void* __restrict__ w1,
            const void* __restrict__ w2, ush* __restrict__ wTb,
            const int* __restrict__ flag) {
  __shared__ ush tile[32][33];
  const void* w = (blockIdx.z == 0) ? w0 : ((blockIdx.z == 1) ? w1 : w2);
  ush* wT = wTb + (long)blockIdx.z * 262144;
  const int bx = blockIdx.x * 32, by = blockIdx.y * 32;
  const int tx = threadIdx.x & 31, ty = threadIdx.x >> 5;
  const int f = *flag;
#pragma unroll
  for (int j = 0; j < 32; j += 8) {
    const int k = by + ty + j, n = bx + tx;
    tile[ty + j][tx] = f ? ((const ush*)w)[k * 512 + n]
                         : f2b(((const float*)w)[k * 512 + n]);
  }
  __syncthreads();
#pragma unroll
  for (int j = 0; j < 32; j += 8)
    wT[(bx + ty + j) * 512 + by + tx] = tile[tx][ty + j];
}

// ---------- kernel: pack biases -> fp32 ----------
__global__ void pack_bias(const void* __restrict__ b0, const void* __restrict__ b1,
                          const void* __restrict__ b2, float* __restrict__ biasf,
                          const int* __restrict__ flag) {
  const void* b = (blockIdx.x == 0) ? b0 : ((blockIdx.x == 1) ? b1 : b2);
  const int n = threadIdx.x;
  const float v = (*flag) ? b2f(((const ush*)b)[n]) : ((const float*)b)[n];
  biasf[blockIdx.x * 512 + n] = v;
}

// ---------- kernel: QKV projection GEMM (m97 structure + T3-min dbuf prefetch) ----------
// 128x128 tile, BK=32, 4 waves. Double-buffered LDS: issue next-tile
// global_load_lds BEFORE ds_read+MFMA of current tile; single barrier per
// K-step drains the prefetch after compute (stage latency hides under MFMA).
__global__ __launch_bounds__(256)
void proj_gemm(const ush* __restrict__ xb, const ush* __restrict__ wTb,
               const float* __restrict__ biasf, ush* __restrict__ qkv) {
  __shared__ ush As[2][4096];  // [buf][128 rows][32 k] bf16, linear
  __shared__ ush Bs[2][4096];

  const int z = blockIdx.z;
  const ush* wt = wTb + (long)z * 262144;
  const float* bias = biasf + z * 512;
  ush* out = qkv + (long)z * NE;

  const int t = threadIdx.x;
  const int lane = t & 63;
  const int wvid = t >> 6;
  const int wm = wvid & 1, wn = wvid >> 1;
  const int col = lane & 15, quad = lane >> 4;

  const long m0 = (long)blockIdx.y * 128;
  const int n0 = blockIdx.x * 128;

  // staging addresses: group g covers tile rows g*16..g*16+15 (1024 B LDS).
  // lane l -> row g*16 + (l>>2), slot (l&3); source k8 pre-swizzled.
  const int r_in_g = lane >> 2;
  const int swz = (((lane & 3) ^ ((r_in_g >> 1) & 3)) * 8);
  const int g0 = wvid * 2, g1 = g0 + 1;
  const ush* gA0 = xb + (m0 + g0 * 16 + r_in_g) * 512 + swz;
  const ush* gA1 = xb + (m0 + g1 * 16 + r_in_g) * 512 + swz;
  const ush* gB0 = wt + (long)(n0 + g0 * 16 + r_in_g) * 512 + swz;
  const ush* gB1 = wt + (long)(n0 + g1 * 16 + r_in_g) * 512 + swz;

  // fragment ds_read offsets (row = 16*i + col  =>  f(row) = (col>>1)&3)
  const int kswz = ((quad ^ ((col >> 1) & 3)) * 8);
  int aofs[4], bofs4[4];
#pragma unroll
  for (int i = 0; i < 4; i++) aofs[i] = (wm * 64 + i * 16 + col) * 32 + kswz;
#pragma unroll
  for (int j = 0; j < 4; j++) bofs4[j] = (wn * 64 + j * 16 + col) * 32 + kswz;

  const f32x4 z4 = {0.f, 0.f, 0.f, 0.f};
  f32x4 acc[4][4];
#pragma unroll
  for (int i = 0; i < 4; i++)
#pragma unroll
    for (int j = 0; j < 4; j++) acc[i][j] = z4;

  // prologue: stage k=0 into buf 0
  gload16(gA0, &As[0][g0 * 512]);
  gload16(gA1, &As[0][g1 * 512]);
  gload16(gB0, &Bs[0][g0 * 512]);
  gload16(gB1, &Bs[0][g1 * 512]);
  __syncthreads();

  int cur = 0;
  for (int k0 = 0; k0 < 512; k0 += 32) {
    const int nk = k0 + 32;
    if (nk < 512) {  // issue prefetch BEFORE compute (overlaps with MFMA below)
      const int nb = cur ^ 1;
      gload16(gA0 + nk, &As[nb][g0 * 512]);
      gload16(gA1 + nk, &As[nb][g1 * 512]);
      gload16(gB0 + nk, &Bs[nb][g0 * 512]);
      gload16(gB1 + nk, &Bs[nb][g1 * 512]);
    }
    bf16x8 a[4], b[4];
#pragma unroll
    for (int i = 0; i < 4; i++) a[i] = bc8(*(const int4*)&As[cur][aofs[i]]);
#pragma unroll
    for (int j = 0; j < 4; j++) b[j] = bc8(*(const int4*)&Bs[cur][bofs4[j]]);
#pragma unroll
    for (int i = 0; i < 4; i++)
#pragma unroll
      for (int j = 0; j < 4; j++)
        acc[i][j] = __builtin_amdgcn_mfma_f32_16x16x32_bf16(a[i], b[j], acc[i][j], 0, 0, 0);
    __syncthreads();  // drains prefetch vmcnt; next tile ready, reads of cur done
    cur ^= 1;
  }

#pragma unroll
  for (int j = 0; j < 4; j++) {
    const int n = n0 + wn * 64 + j * 16 + col;
    const float bb = bias[n];
#pragma unroll
    for (int i = 0; i < 4; i++) {
      const long row0 = m0 + wm * 64 + i * 16 + quad * 4;
#pragma unroll
      for (int r = 0; r < 4; r++)
        out[(row0 + r) * 512 + n] = f2b(acc[i][j][r] + bb);
    }
  }
}

// ---------- MFMA axial attention ----------
// PASS 1 (column): block (b,n,w); rows = H; writes xv in-place over V (bf16),
//                  via LDS-staged full-line int4 stores.
// PASS 2 (row):    block (b,n,h); rows = W; writes xu to a CONTIGUOUS fp32
//                  intermediate [bz][n][h][w][d] (out_interleave finishes).
#define QS_STRIDE 72    // bf16, 144 B rows (16B aligned), uniform bank groups
#define VT_STRIDE 136   // Vt[d][g], 272 B rows
#define P_STRIDE  136
#define OS_STRIDE 72    // pass-1 output staging rows (16B aligned)

__device__ __forceinline__ int vt_idx(int d, int g) {
  return d * VT_STRIDE + ((((g >> 3) ^ ((d >> 3) & 7)) << 3) | (g & 7));
}

template<int PASS>
__global__ __launch_bounds__(256, 3)
void axial_attn_mfma(const ush* __restrict__ Qb, const ush* __restrict__ Kb,
                     ush* __restrict__ Vb, float* __restrict__ xuf,
                     const int bofs) {
  __shared__ ush smem[27136];          // 54272 B
  ush* Qs = smem;                      // [128][72]
  ush* Ks = smem + 9216;               // [128][72]
  ush* Vt = smem + 18432;              // [64][136] swizzled
  ush* P  = smem;                      // [128][136] overlays Qs+Ks after barrier1

  const int b = blockIdx.z + bofs, n = blockIdx.y, pp = blockIdx.x;
  long base; int stride;
  if (PASS == 1) { base = ((long)b * 16384 + pp) * 512 + n * 64; stride = 65536; }
  else           { base = ((long)(b * 128 + pp) * 128) * 512 + n * 64; stride = 512; }

  const int t = threadIdx.x;
  // phase 0: stage Q,K row-major; V transposed (swizzled)
#pragma unroll
  for (int it = 0; it < 4; it++) {
    const int c = t + it * 256;
    const int row = c >> 3, c8 = c & 7;
    const long g = base + (long)row * stride + c8 * 8;
    int4 q = *(const int4*)(Qb + g);
    int4 k = *(const int4*)(Kb + g);
    int4 v = *(const int4*)(Vb + g);
    *(int4*)&Qs[row * QS_STRIDE + c8 * 8] = q;
    *(int4*)&Ks[row * QS_STRIDE + c8 * 8] = k;
    union { int4 i4; ush u[8]; } vu; vu.i4 = v;
#pragma unroll
    for (int dd = 0; dd < 8; dd++)
      Vt[vt_idx(c8 * 8 + dd, row)] = vu.u[dd];
  }
  __syncthreads();

  const int lane = t & 63, wv = t >> 6;
  const int col = lane & 15, quad = lane >> 4;
  const int m0 = wv * 32;  // wave owns rows m0..m0+31, all 128 cols
  const f32x4 z4 = {0.f, 0.f, 0.f, 0.f};

  // ---- S = Q K^T : 2 m-tiles x 8 n-tiles x 2 k-steps ----
  f32x4 sacc[2][8];
#pragma unroll
  for (int i = 0; i < 2; i++)
#pragma unroll
    for (int j = 0; j < 8; j++) sacc[i][j] = z4;
  __builtin_amdgcn_s_setprio(1);
#pragma unroll
  for (int k0 = 0; k0 < 64; k0 += 32) {
    bf16x8 a[2], kb[8];
#pragma unroll
    for (int i = 0; i < 2; i++)
      a[i] = bc8(*(const int4*)&Qs[(m0 + i * 16 + col) * QS_STRIDE + k0 + quad * 8]);
#pragma unroll
    for (int j = 0; j < 8; j++)
      kb[j] = bc8(*(const int4*)&Ks[(j * 16 + col) * QS_STRIDE + k0 + quad * 8]);
#pragma unroll
    for (int i = 0; i < 2; i++)
#pragma unroll
      for (int j = 0; j < 8; j++)
        sacc[i][j] = __builtin_amdgcn_mfma_f32_16x16x32_bf16(a[i], kb[j], sacc[i][j], 0, 0, 0);
  }
  __builtin_amdgcn_s_setprio(0);

  // ---- softmax (faithful: clip +-(1-eps), /8, exp, sum, clip [eps,1-eps]) ----
  const float CLIP = 1.0f - 1e-7f;
  float e[2][8][4], inv[2][4];
#pragma unroll
  for (int i = 0; i < 2; i++)
#pragma unroll
    for (int r = 0; r < 4; r++) {
      float part = 0.f;
#pragma unroll
      for (int j = 0; j < 8; j++) {
        float s = sacc[i][j][r];
        s = fminf(fmaxf(s, -CLIP), CLIP) * 0.125f;
        const float ee = __expf(s);
        e[i][j][r] = ee;
        part += ee;
      }
      part += __shfl_xor(part, 1);
      part += __shfl_xor(part, 2);
      part += __shfl_xor(part, 4);
      part += __shfl_xor(part, 8);
      inv[i][r] = 1.0f / part;
    }
  __syncthreads();  // barrier1: all Qs/Ks reads complete -> safe to overlay P

  // lane's rows: m0 + 16i + 4*quad + r; cols: 16j + col (C/D layout, m89)
#pragma unroll
  for (int i = 0; i < 2; i++)
#pragma unroll
    for (int r = 0; r < 4; r++) {
      const int row = m0 + i * 16 + quad * 4 + r;
#pragma unroll
      for (int j = 0; j < 8; j++) {
        const float pv = fminf(fmaxf(e[i][j][r] * inv[i][r], 1e-7f), CLIP);
        P[row * P_STRIDE + j * 16 + col] = f2b(pv);
      }
    }
  __syncthreads();  // barrier2: P complete

  // ---- xv = P V : 2 m-tiles x 4 n-tiles x 4 k-steps ----
  f32x4 oacc[2][4];
#pragma unroll
  for (int i = 0; i < 2; i++)
#pragma unroll
    for (int j = 0; j < 4; j++) oacc[i][j] = z4;
  __builtin_amdgcn_s_setprio(1);
#pragma unroll
  for (int k0 = 0; k0 < 128; k0 += 32) {
    bf16x8 a[2], vb[4];
#pragma unroll
    for (int i = 0; i < 2; i++)
      a[i] = bc8(*(const int4*)&P[(m0 + i * 16 + col) * P_STRIDE + k0 + quad * 8]);
#pragma unroll
    for (int j = 0; j < 4; j++)
      vb[j] = bc8(*(const int4*)&Vt[vt_idx(j * 16 + col, k0 + quad * 8)]);
#pragma unroll
    for (int i = 0; i < 2; i++)
#pragma unroll
      for (int j = 0; j < 4; j++)
        oacc[i][j] = __builtin_amdgcn_mfma_f32_16x16x32_bf16(a[i], vb[j], oacc[i][j], 0, 0, 0);
  }
  __builtin_amdgcn_s_setprio(0);

  // ---- epilogue ----
  if (PASS == 1) {
    // stage to LDS (reuse P region), then full-line int4 stores
    __syncthreads();  // all P/Vt reads complete
    ush* Os = smem;   // [128][72]
#pragma unroll
    for (int i = 0; i < 2; i++)
#pragma unroll
      for (int r = 0; r < 4; r++) {
        const int row = m0 + i * 16 + quad * 4 + r;
#pragma unroll
        for (int j = 0; j < 4; j++)
          Os[row * OS_STRIDE + j * 16 + col] = f2b(oacc[i][j][r]);
      }
    __syncthreads();
#pragma unroll
    for (int it = 0; it < 4; it++) {
      const int g2 = t + it * 256;
      const int row = g2 >> 3, c8 = g2 & 7;
      *(int4*)&Vb[base + (long)row * stride + c8 * 8] =
          *(const int4*)&Os[row * OS_STRIDE + c8 * 8];
    }
  } else {
    // contiguous fp32 intermediate xu[bz][n][h(pp)][w(row)][d]
    const long xbase = (((long)(blockIdx.z * 8 + n) * 128 + pp) * 128) * 64;
#pragma unroll
    for (int i = 0; i < 2; i++)
#pragma unroll
      for (int r = 0; r < 4; r++) {
        const int row = m0 + i * 16 + quad * 4 + r;
#pragma unroll
        for (int j = 0; j < 4; j++)
          xuf[xbase + (long)row * 64 + j * 16 + col] = oacc[i][j][r];
      }
  }
}

// ---------- kernel: xu[bz][n][h][w][d] -> out[b][h][w][d*8+n], coalesced ----------
// LDS [8][16][64] fp32 with per-n d-rotation (d+8n)&63: staging float4 writes
// land 2-way max; gather reads (4 consecutive n, same d) hit 4 distinct banks.
__global__ __launch_bounds__(256)
void out_interleave(const float* __restrict__ xu, void* __restrict__ outp,
                    const int* __restrict__ flagp, const int bofs) {
  __shared__ float lds[8192];  // 32 KB
  const int bz = blockIdx.z, h = blockIdx.y, w0 = blockIdx.x * 16;
  const int t = threadIdx.x;
#pragma unroll
  for (int n = 0; n < 8; n++) {
    const float* src = xu + ((((long)(bz * 8 + n)) * 128 + h) * 128 + w0) * 64;
    const int e = t * 4, w = e >> 6, d = e & 63;
    const float4 v = *(const float4*)&src[e];
    const int dr = (d + n * 8) & 63;  // no wrap inside float4 (d%4==0, rot%8==0)
    *(float4*)&lds[(n * 16 + w) * 64 + dr] = v;
  }
  __syncthreads();
  const int flg = *flagp;
  const long obase = (((long)(bz + bofs) * 128 + h) * 128 + w0) * 512;
  const int tc = t & 127, c0 = tc * 4;
  const int d = c0 >> 3, n0 = c0 & 7;  // n0 in {0,4}; c0..c0+3 share d
#pragma unroll
  for (int ro = 0; ro < 8; ro++) {
    const int w = (t >> 7) * 8 + ro;
    float r[4];
#pragma unroll
    for (int k = 0; k < 4; k++) {
      const int n = n0 + k;
      r[k] = lds[(n * 16 + w) * 64 + ((d + n * 8) & 63)];
    }
    const long oi = obase + (long)w * 512 + c0;
    if (flg) {
      union { ush u[4]; int2 v; } o;
      o.u[0] = f2b(r[0]); o.u[1] = f2b(r[1]);
      o.u[2] = f2b(r[2]); o.u[3] = f2b(r[3]);
      *(int2*)&((ush*)outp)[oi] = o.v;
    } else {
      float4 o; o.x = r[0]; o.y = r[1]; o.z = r[2]; o.w = r[3];
      *(float4*)&((float*)outp)[oi] = o;
    }
  }
}

// ---------- host ----------
extern "C" void kernel_launch(void* const* d_in, const int* in_sizes, int n_in,
                              void* d_out, int out_size, void* d_ws, size_t ws_size,
                              hipStream_t stream) {
  const void* x  = d_in[0];
  const void* wq = d_in[1];
  const void* bq = d_in[2];
  const void* wk = d_in[3];
  const void* bk = d_in[4];
  const void* wv = d_in[5];
  const void* bv = d_in[6];

  char* ws = (char*)d_ws;
  int*   flag  = (int*)ws;                       // @0
  float* biasf = (float*)(ws + 256);             // 3*512 fp32
  ush*   wTb   = (ush*)(ws + 8192);              // 1.5 MB
  ush*   xb    = (ush*)(ws + 8192 + 1572864);    // 64 MB (xu reuses after proj)
  float* xuf   = (float*)(ws + 8192 + 1572864);  // 64 MB fp32 = 2 b's of xu
  ush*   qkv   = (ush*)(ws + 8192 + 1572864 + 67108864);  // 3*64 MB bf16

  dim3 blk(256);
  detect_dtype<<<1, blk, 0, stream>>>((const ush*)x, flag);
  pack_bias<<<3, 512, 0, stream>>>(bq, bk, bv, biasf, flag);
  pack_w<<<dim3(16, 16, 3), blk, 0, stream>>>(wq, wk, wv, wTb, flag);
  pack_x<<<16384, blk, 0, stream>>>(x, xb, flag);

  ush* Q = qkv;
  ush* K = Q + NE;
  ush* V = K + NE;
  proj_gemm<<<dim3(4, 512, 3), blk, 0, stream>>>(xb, wTb, biasf, Q);
  axial_attn_mfma<1><<<dim3(128, 8, 4), blk, 0, stream>>>(Q, K, V, nullptr, 0);
  // pass 2 in two b-halves so the fp32 xu intermediate fits in the dead xb region
  for (int half = 0; half < 2; half++) {
    axial_attn_mfma<2><<<dim3(128, 8, 2), blk, 0, stream>>>(Q, K, V, xuf, half * 2);
    out_interleave<<<dim3(8, 128, 2), blk, 0, stream>>>(xuf, d_out, flag, half * 2);
  }
}

// Round 3
// 546.716 us; speedup vs baseline: 1.6061x; 1.0791x over previous
//
#include <hip/hip_runtime.h>

typedef unsigned short ush;
typedef __attribute__((ext_vector_type(8))) __bf16 bf16x8;
typedef __attribute__((ext_vector_type(4))) float f32x4;

#define NE 33554432L  // 4*128*128*512 elements per Q/K/V matrix

// ---------- bf16 <-> fp32 helpers (RNE) ----------
__device__ __forceinline__ float b2f(ush u) {
  return __uint_as_float(((unsigned int)u) << 16);
}
__device__ __forceinline__ ush f2b(float f) {
  unsigned int x = __float_as_uint(f);
  x += 0x7fffu + ((x >> 16) & 1u);
  return (ush)(x >> 16);
}
__device__ __forceinline__ bf16x8 bc8(int4 v) { return __builtin_bit_cast(bf16x8, v); }

// async 16B global->LDS (wave-uniform LDS base + lane*16)
__device__ __forceinline__ void gload16(const ush* g, ush* l) {
  __builtin_amdgcn_global_load_lds(
      (const __attribute__((address_space(1))) void*)g,
      (__attribute__((address_space(3))) void*)l, 16, 0, 0);
}

// ---------- kernel: input dtype sniffer ----------
__global__ __launch_bounds__(256)
void detect_dtype(const ush* __restrict__ x, int* __restrict__ flag) {
  __shared__ int red[256];
  const int t = threadIdx.x;
  int cnt = 0;
  for (int i = t; i < 16384; i += 256) {
    const int e = (x[i] >> 7) & 0xFF;
    cnt += (e == 0 || (e >= 100 && e <= 142)) ? 1 : 0;
  }
  red[t] = cnt;
  __syncthreads();
  for (int s = 128; s > 0; s >>= 1) {
    if (t < s) red[t] += red[t + s];
    __syncthreads();
  }
  if (t == 0) flag[0] = (red[0] >= 13107) ? 1 : 0;  // 80% of 16384
}

// ---------- kernel: pack x -> bf16 ----------
__global__ __launch_bounds__(256)
void pack_x(const void* __restrict__ xin, ush* __restrict__ xb,
            const int* __restrict__ flag) {
  const long i0 = ((long)blockIdx.x * 256 + threadIdx.x) * 8;
  if (*flag) {
    *(int4*)&xb[i0] = *(const int4*)&((const ush*)xin)[i0];
  } else {
    const float* xf = (const float*)xin;
    const float4 a = *(const float4*)&xf[i0];
    const float4 b = *(const float4*)&xf[i0 + 4];
    union { ush u[8]; int4 v; } r;
    r.u[0] = f2b(a.x); r.u[1] = f2b(a.y); r.u[2] = f2b(a.z); r.u[3] = f2b(a.w);
    r.u[4] = f2b(b.x); r.u[5] = f2b(b.y); r.u[6] = f2b(b.z); r.u[7] = f2b(b.w);
    *(int4*)&xb[i0] = r.v;
  }
}

// ---------- kernel: pack+transpose weights -> bf16 wT[n][k] = w[k][n] ----------
__global__ __launch_bounds__(256)
void pack_w(const void* __restrict__ w0, const void* __restrict__ w1,
            const void* __restrict__ w2, ush* __restrict__ wTb,
            const int* __restrict__ flag) {
  __shared__ ush tile[32][33];
  const void* w = (blockIdx.z == 0) ? w0 : ((blockIdx.z == 1) ? w1 : w2);
  ush* wT = wTb + (long)blockIdx.z * 262144;
  const int bx = blockIdx.x * 32, by = blockIdx.y * 32;
  const int tx = threadIdx.x & 31, ty = threadIdx.x >> 5;
  const int f = *flag;
#pragma unroll
  for (int j = 0; j < 32; j += 8) {
    const int k = by + ty + j, n = bx + tx;
    tile[ty + j][tx] = f ? ((const ush*)w)[k * 512 + n]
                         : f2b(((const float*)w)[k * 512 + n]);
  }
  __syncthreads();
#pragma unroll
  for (int j = 0; j < 32; j += 8)
    wT[(bx + ty + j) * 512 + by + tx] = tile[tx][ty + j];
}

// ---------- kernel: pack biases -> fp32 ----------
__global__ void pack_bias(const void* __restrict__ b0, const void* __restrict__ b1,
                          const void* __restrict__ b2, float* __restrict__ biasf,
                          const int* __restrict__ flag) {
  const void* b = (blockIdx.x == 0) ? b0 : ((blockIdx.x == 1) ? b1 : b2);
  const int n = threadIdx.x;
  const float v = (*flag) ? b2f(((const ush*)b)[n]) : ((const float*)b)[n];
  biasf[blockIdx.x * 512 + n] = v;
}

// ---------- kernel: QKV projection GEMM (m97 + dbuf prefetch + XCD swizzle) ----------
// 128x128 tile, BK=32, 4 waves, double-buffered global_load_lds prefetch.
// T1 XCD swizzle: nwg=6144 (%8==0). Consecutive NEW tile indices (which share
// the 128KB A-tile across the 4 n-blocks) map to one XCD's contiguous chunk,
// so A-tile re-reads hit that XCD's private L2 instead of re-fetching HBM.
__global__ __launch_bounds__(256)
void proj_gemm(const ush* __restrict__ xb, const ush* __restrict__ wTb,
               const float* __restrict__ biasf, ush* __restrict__ qkv) {
  __shared__ ush As[2][4096];  // [buf][128 rows][32 k] bf16, linear
  __shared__ ush Bs[2][4096];

  // ---- XCD-aware remap of (x,y,z) ----
  const int lin = blockIdx.x + (blockIdx.y << 2) + (blockIdx.z << 11);
  const int swz = ((lin & 7) * 768) + (lin >> 3);  // 768 = 6144/8
  const int z   = swz >> 11;        // /2048 (=4*512)
  const int rem = swz & 2047;
  const int by  = rem >> 2, bx = rem & 3;

  const ush* wt = wTb + (long)z * 262144;
  const float* bias = biasf + z * 512;
  ush* out = qkv + (long)z * NE;

  const int t = threadIdx.x;
  const int lane = t & 63;
  const int wvid = t >> 6;
  const int wm = wvid & 1, wn = wvid >> 1;
  const int col = lane & 15, quad = lane >> 4;

  const long m0 = (long)by * 128;
  const int n0 = bx * 128;

  // staging addresses: group g covers tile rows g*16..g*16+15 (1024 B LDS).
  // lane l -> row g*16 + (l>>2), slot (l&3); source k8 pre-swizzled.
  const int r_in_g = lane >> 2;
  const int swzk = (((lane & 3) ^ ((r_in_g >> 1) & 3)) * 8);
  const int g0 = wvid * 2, g1 = g0 + 1;
  const ush* gA0 = xb + (m0 + g0 * 16 + r_in_g) * 512 + swzk;
  const ush* gA1 = xb + (m0 + g1 * 16 + r_in_g) * 512 + swzk;
  const ush* gB0 = wt + (long)(n0 + g0 * 16 + r_in_g) * 512 + swzk;
  const ush* gB1 = wt + (long)(n0 + g1 * 16 + r_in_g) * 512 + swzk;

  // fragment ds_read offsets (row = 16*i + col  =>  f(row) = (col>>1)&3)
  const int kswz = ((quad ^ ((col >> 1) & 3)) * 8);
  int aofs[4], bofs4[4];
#pragma unroll
  for (int i = 0; i < 4; i++) aofs[i] = (wm * 64 + i * 16 + col) * 32 + kswz;
#pragma unroll
  for (int j = 0; j < 4; j++) bofs4[j] = (wn * 64 + j * 16 + col) * 32 + kswz;

  const f32x4 z4 = {0.f, 0.f, 0.f, 0.f};
  f32x4 acc[4][4];
#pragma unroll
  for (int i = 0; i < 4; i++)
#pragma unroll
    for (int j = 0; j < 4; j++) acc[i][j] = z4;

  // prologue: stage k=0 into buf 0
  gload16(gA0, &As[0][g0 * 512]);
  gload16(gA1, &As[0][g1 * 512]);
  gload16(gB0, &Bs[0][g0 * 512]);
  gload16(gB1, &Bs[0][g1 * 512]);
  __syncthreads();

  int cur = 0;
  for (int k0 = 0; k0 < 512; k0 += 32) {
    const int nk = k0 + 32;
    if (nk < 512) {  // issue prefetch BEFORE compute (overlaps with MFMA below)
      const int nb = cur ^ 1;
      gload16(gA0 + nk, &As[nb][g0 * 512]);
      gload16(gA1 + nk, &As[nb][g1 * 512]);
      gload16(gB0 + nk, &Bs[nb][g0 * 512]);
      gload16(gB1 + nk, &Bs[nb][g1 * 512]);
    }
    bf16x8 a[4], b[4];
#pragma unroll
    for (int i = 0; i < 4; i++) a[i] = bc8(*(const int4*)&As[cur][aofs[i]]);
#pragma unroll
    for (int j = 0; j < 4; j++) b[j] = bc8(*(const int4*)&Bs[cur][bofs4[j]]);
#pragma unroll
    for (int i = 0; i < 4; i++)
#pragma unroll
      for (int j = 0; j < 4; j++)
        acc[i][j] = __builtin_amdgcn_mfma_f32_16x16x32_bf16(a[i], b[j], acc[i][j], 0, 0, 0);
    __syncthreads();  // drains prefetch vmcnt; next tile ready, reads of cur done
    cur ^= 1;
  }

#pragma unroll
  for (int j = 0; j < 4; j++) {
    const int n = n0 + wn * 64 + j * 16 + col;
    const float bb = bias[n];
#pragma unroll
    for (int i = 0; i < 4; i++) {
      const long row0 = m0 + wm * 64 + i * 16 + quad * 4;
#pragma unroll
      for (int r = 0; r < 4; r++)
        out[(row0 + r) * 512 + n] = f2b(acc[i][j][r] + bb);
    }
  }
}

// ---------- MFMA axial attention (512 threads, 8 waves, 16 rows/wave) ----------
// PASS 1 (column): block (b,n,w); rows = H; writes xv in-place over V (bf16),
//                  via LDS-staged full-line int4 stores.
// PASS 2 (row):    block (b,n,h); rows = W; writes xu to a CONTIGUOUS fp32
//                  intermediate [bz][n][h][w][d] (out_interleave finishes).
// 54272 B LDS -> 2 blocks/CU x 8 waves = 16 waves/CU (was 12 with 256-thr).
#define QS_STRIDE 72    // bf16, 144 B rows (16B aligned), uniform bank groups
#define VT_STRIDE 136   // Vt[d][g], 272 B rows
#define P_STRIDE  136
#define OS_STRIDE 72    // pass-1 output staging rows (16B aligned)

__device__ __forceinline__ int vt_idx(int d, int g) {
  return d * VT_STRIDE + ((((g >> 3) ^ ((d >> 3) & 7)) << 3) | (g & 7));
}

template<int PASS>
__global__ __launch_bounds__(512, 4)
void axial_attn_mfma(const ush* __restrict__ Qb, const ush* __restrict__ Kb,
                     ush* __restrict__ Vb, float* __restrict__ xuf,
                     const int bofs) {
  __shared__ ush smem[27136];          // 54272 B
  ush* Qs = smem;                      // [128][72]
  ush* Ks = smem + 9216;               // [128][72]
  ush* Vt = smem + 18432;              // [64][136] swizzled
  ush* P  = smem;                      // [128][136] overlays Qs+Ks after barrier1

  const int b = blockIdx.z + bofs, n = blockIdx.y, pp = blockIdx.x;
  long base; int stride;
  if (PASS == 1) { base = ((long)b * 16384 + pp) * 512 + n * 64; stride = 65536; }
  else           { base = ((long)(b * 128 + pp) * 128) * 512 + n * 64; stride = 512; }

  const int t = threadIdx.x;
  // phase 0: stage Q,K row-major; V transposed (swizzled)
#pragma unroll
  for (int it = 0; it < 2; it++) {
    const int c = t + it * 512;
    const int row = c >> 3, c8 = c & 7;
    const long g = base + (long)row * stride + c8 * 8;
    int4 q = *(const int4*)(Qb + g);
    int4 k = *(const int4*)(Kb + g);
    int4 v = *(const int4*)(Vb + g);
    *(int4*)&Qs[row * QS_STRIDE + c8 * 8] = q;
    *(int4*)&Ks[row * QS_STRIDE + c8 * 8] = k;
    union { int4 i4; ush u[8]; } vu; vu.i4 = v;
#pragma unroll
    for (int dd = 0; dd < 8; dd++)
      Vt[vt_idx(c8 * 8 + dd, row)] = vu.u[dd];
  }
  __syncthreads();

  const int lane = t & 63, wv = t >> 6;   // wv in [0,8)
  const int col = lane & 15, quad = lane >> 4;
  const int m0 = wv * 16;  // wave owns rows m0..m0+15, all 128 cols
  const f32x4 z4 = {0.f, 0.f, 0.f, 0.f};

  // ---- S = Q K^T : 1 m-tile x 8 n-tiles x 2 k-steps ----
  f32x4 sacc[8];
#pragma unroll
  for (int j = 0; j < 8; j++) sacc[j] = z4;
  __builtin_amdgcn_s_setprio(1);
#pragma unroll
  for (int k0 = 0; k0 < 64; k0 += 32) {
    bf16x8 a, kb[8];
    a = bc8(*(const int4*)&Qs[(m0 + col) * QS_STRIDE + k0 + quad * 8]);
#pragma unroll
    for (int j = 0; j < 8; j++)
      kb[j] = bc8(*(const int4*)&Ks[(j * 16 + col) * QS_STRIDE + k0 + quad * 8]);
#pragma unroll
    for (int j = 0; j < 8; j++)
      sacc[j] = __builtin_amdgcn_mfma_f32_16x16x32_bf16(a, kb[j], sacc[j], 0, 0, 0);
  }
  __builtin_amdgcn_s_setprio(0);

  // ---- softmax (faithful: clip +-(1-eps), /8, exp, sum, clip [eps,1-eps]) ----
  const float CLIP = 1.0f - 1e-7f;
  float e[8][4], inv[4];
#pragma unroll
  for (int r = 0; r < 4; r++) {
    float part = 0.f;
#pragma unroll
    for (int j = 0; j < 8; j++) {
      float s = sacc[j][r];
      s = fminf(fmaxf(s, -CLIP), CLIP) * 0.125f;
      const float ee = __expf(s);
      e[j][r] = ee;
      part += ee;
    }
    part += __shfl_xor(part, 1);
    part += __shfl_xor(part, 2);
    part += __shfl_xor(part, 4);
    part += __shfl_xor(part, 8);
    inv[r] = 1.0f / part;
  }
  __syncthreads();  // barrier1: all Qs/Ks reads complete -> safe to overlay P

  // lane's rows: m0 + 4*quad + r; cols: 16j + col (C/D layout, m89)
#pragma unroll
  for (int r = 0; r < 4; r++) {
    const int row = m0 + quad * 4 + r;
#pragma unroll
    for (int j = 0; j < 8; j++) {
      const float pv = fminf(fmaxf(e[j][r] * inv[r], 1e-7f), CLIP);
      P[row * P_STRIDE + j * 16 + col] = f2b(pv);
    }
  }
  __syncthreads();  // barrier2: P complete

  // ---- xv = P V : 1 m-tile x 4 n-tiles x 4 k-steps ----
  f32x4 oacc[4];
#pragma unroll
  for (int j = 0; j < 4; j++) oacc[j] = z4;
  __builtin_amdgcn_s_setprio(1);
#pragma unroll
  for (int k0 = 0; k0 < 128; k0 += 32) {
    bf16x8 a, vb[4];
    a = bc8(*(const int4*)&P[(m0 + col) * P_STRIDE + k0 + quad * 8]);
#pragma unroll
    for (int j = 0; j < 4; j++)
      vb[j] = bc8(*(const int4*)&Vt[vt_idx(j * 16 + col, k0 + quad * 8)]);
#pragma unroll
    for (int j = 0; j < 4; j++)
      oacc[j] = __builtin_amdgcn_mfma_f32_16x16x32_bf16(a, vb[j], oacc[j], 0, 0, 0);
  }
  __builtin_amdgcn_s_setprio(0);

  // ---- epilogue ----
  if (PASS == 1) {
    // stage to LDS (reuse P region), then full-line int4 stores
    __syncthreads();  // all P/Vt reads complete
    ush* Os = smem;   // [128][72]
#pragma unroll
    for (int r = 0; r < 4; r++) {
      const int row = m0 + quad * 4 + r;
#pragma unroll
      for (int j = 0; j < 4; j++)
        Os[row * OS_STRIDE + j * 16 + col] = f2b(oacc[j][r]);
    }
    __syncthreads();
#pragma unroll
    for (int it = 0; it < 2; it++) {
      const int g2 = t + it * 512;
      const int row = g2 >> 3, c8 = g2 & 7;
      *(int4*)&Vb[base + (long)row * stride + c8 * 8] =
          *(const int4*)&Os[row * OS_STRIDE + c8 * 8];
    }
  } else {
    // contiguous fp32 intermediate xu[bz][n][h(pp)][w(row)][d]
    const long xbase = (((long)(blockIdx.z * 8 + n) * 128 + pp) * 128) * 64;
#pragma unroll
    for (int r = 0; r < 4; r++) {
      const int row = m0 + quad * 4 + r;
#pragma unroll
      for (int j = 0; j < 4; j++)
        xuf[xbase + (long)row * 64 + j * 16 + col] = oacc[j][r];
    }
  }
}

// ---------- kernel: xu[bz][n][h][w][d] -> out[b][h][w][d*8+n], coalesced ----------
// LDS [8][16][64] fp32 with per-n d-rotation (d+8n)&63: staging float4 writes
// land 2-way max; gather reads (4 consecutive n, same d) hit 4 distinct banks.
__global__ __launch_bounds__(256)
void out_interleave(const float* __restrict__ xu, void* __restrict__ outp,
                    const int* __restrict__ flagp, const int bofs) {
  __shared__ float lds[8192];  // 32 KB
  const int bz = blockIdx.z, h = blockIdx.y, w0 = blockIdx.x * 16;
  const int t = threadIdx.x;
#pragma unroll
  for (int n = 0; n < 8; n++) {
    const float* src = xu + ((((long)(bz * 8 + n)) * 128 + h) * 128 + w0) * 64;
    const int e = t * 4, w = e >> 6, d = e & 63;
    const float4 v = *(const float4*)&src[e];
    const int dr = (d + n * 8) & 63;  // no wrap inside float4 (d%4==0, rot%8==0)
    *(float4*)&lds[(n * 16 + w) * 64 + dr] = v;
  }
  __syncthreads();
  const int flg = *flagp;
  const long obase = (((long)(bz + bofs) * 128 + h) * 128 + w0) * 512;
  const int tc = t & 127, c0 = tc * 4;
  const int d = c0 >> 3, n0 = c0 & 7;  // n0 in {0,4}; c0..c0+3 share d
#pragma unroll
  for (int ro = 0; ro < 8; ro++) {
    const int w = (t >> 7) * 8 + ro;
    float r[4];
#pragma unroll
    for (int k = 0; k < 4; k++) {
      const int n = n0 + k;
      r[k] = lds[(n * 16 + w) * 64 + ((d + n * 8) & 63)];
    }
    const long oi = obase + (long)w * 512 + c0;
    if (flg) {
      union { ush u[4]; int2 v; } o;
      o.u[0] = f2b(r[0]); o.u[1] = f2b(r[1]);
      o.u[2] = f2b(r[2]); o.u[3] = f2b(r[3]);
      *(int2*)&((ush*)outp)[oi] = o.v;
    } else {
      float4 o; o.x = r[0]; o.y = r[1]; o.z = r[2]; o.w = r[3];
      *(float4*)&((float*)outp)[oi] = o;
    }
  }
}

// ---------- host ----------
extern "C" void kernel_launch(void* const* d_in, const int* in_sizes, int n_in,
                              void* d_out, int out_size, void* d_ws, size_t ws_size,
                              hipStream_t stream) {
  const void* x  = d_in[0];
  const void* wq = d_in[1];
  const void* bq = d_in[2];
  const void* wk = d_in[3];
  const void* bk = d_in[4];
  const void* wv = d_in[5];
  const void* bv = d_in[6];

  char* ws = (char*)d_ws;
  int*   flag  = (int*)ws;                       // @0
  float* biasf = (float*)(ws + 256);             // 3*512 fp32
  ush*   wTb   = (ush*)(ws + 8192);              // 1.5 MB
  ush*   xb    = (ush*)(ws + 8192 + 1572864);    // 64 MB (xu reuses after proj)
  float* xuf   = (float*)(ws + 8192 + 1572864);  // 64 MB fp32 = 2 b's of xu
  ush*   qkv   = (ush*)(ws + 8192 + 1572864 + 67108864);  // 3*64 MB bf16

  dim3 blk(256);
  detect_dtype<<<1, blk, 0, stream>>>((const ush*)x, flag);
  pack_bias<<<3, 512, 0, stream>>>(bq, bk, bv, biasf, flag);
  pack_w<<<dim3(16, 16, 3), blk, 0, stream>>>(wq, wk, wv, wTb, flag);
  pack_x<<<16384, blk, 0, stream>>>(x, xb, flag);

  ush* Q = qkv;
  ush* K = Q + NE;
  ush* V = K + NE;
  proj_gemm<<<dim3(4, 512, 3), blk, 0, stream>>>(xb, wTb, biasf, Q);
  axial_attn_mfma<1><<<dim3(128, 8, 4), dim3(512), 0, stream>>>(Q, K, V, nullptr, 0);
  // pass 2 in two b-halves so the fp32 xu intermediate fits in the dead xb region
  for (int half = 0; half < 2; half++) {
    axial_attn_mfma<2><<<dim3(128, 8, 2), dim3(512), 0, stream>>>(Q, K, V, xuf, half * 2);
    out_interleave<<<dim3(8, 128, 2), blk, 0, stream>>>(xuf, d_out, flag, half * 2);
  }
}